// Round 4
// baseline (367.688 us; speedup 1.0000x reference)
//
#include <hip/hip_runtime.h>
#include <math.h>

#define N_PTS 16384
#define K_NBR 16
#define H_DIM 64
#define TS    2048   // kNN LDS tile (points)
#define MLP_PW 4     // points per wave in mlp

// ---------------- xx[i] = sum(x[i]^2), mimicking numpy squares-then-sum ----
__global__ __launch_bounds__(256) void xx_kernel(const float4* __restrict__ x4,
                                                 float* __restrict__ xx) {
    int i = blockIdx.x * 256 + threadIdx.x;
    float4 v = x4[i];
    {
#pragma clang fp contract(off)
        float s0 = v.x * v.x;
        float s1 = v.y * v.y;
        float s2 = v.z * v.z;
        float s3 = v.w * v.w;
        xx[i] = ((s0 + s1) + s2) + s3;
    }
}

// ---------------- brute-force kNN: 4 rows per wave, 4 waves per block ------
// Wave-shared top-16 per row as an UNSORTED set on lanes 0..15 (set semantics
// suffice: downstream mean over K is order-invariant; strict p>tau keeps the
// lowest index on boundary ties, matching top_k). Insert = replace-min +
// butterfly min-reduce to refresh tau.
__global__ __launch_bounds__(256) void knn_kernel(const float4* __restrict__ x4,
                                                  const float* __restrict__ xx,
                                                  int* __restrict__ knn) {
    __shared__ float4 xs[TS];
    __shared__ float  nxxs[TS];
    const int lane = threadIdx.x & 63;
    const int wave = threadIdx.x >> 6;
    const int row0 = blockIdx.x * 16 + wave * 4;

    float4 y[4];          // 2*xi (exact)
    float  nxxi[4];       // -xx[row]
#pragma unroll
    for (int r = 0; r < 4; ++r) {
        float4 t = x4[row0 + r];
        y[r] = make_float4(2.0f * t.x, 2.0f * t.y, 2.0f * t.z, 2.0f * t.w);
        nxxi[r] = -xx[row0 + r];
    }

    float vlist[4]; int ilist[4]; float tau[4];
#pragma unroll
    for (int r = 0; r < 4; ++r) {
        vlist[r] = (lane < 16) ? -INFINITY : INFINITY;  // upper lanes inert for min
        ilist[r] = -1;
        tau[r]   = -INFINITY;
    }

    for (int t = 0; t < N_PTS / TS; ++t) {
        const int base = t * TS;
        __syncthreads();
        for (int i = threadIdx.x; i < TS; i += 256) {
            xs[i]   = x4[base + i];
            nxxs[i] = -xx[base + i];
        }
        __syncthreads();

        for (int c = lane; c < TS; c += 64) {
            const float4 xj = xs[c];
            const float  nx = nxxs[c];
            const int  cidx = base + c;
            float p[4];
            unsigned long long m[4];
#pragma unroll
            for (int r = 0; r < 4; ++r) {
                // p = 2*xi.xj - xxi - xxj, fma chain
                p[r] = fmaf(y[r].x, xj.x, fmaf(y[r].y, xj.y,
                        fmaf(y[r].z, xj.z, fmaf(y[r].w, xj.w, nx + nxxi[r]))));
                m[r] = __ballot(p[r] > tau[r]);
            }
            if (m[0] | m[1] | m[2] | m[3]) {   // rare, wave-uniform branch
#pragma unroll
                for (int r = 0; r < 4; ++r) {
                    while (m[r]) {
                        const int l = __ffsll(m[r]) - 1;      // lowest lane = lowest idx
                        const float pb = __uint_as_float(
                            __builtin_amdgcn_readlane(__float_as_uint(p[r]), l));
                        const int ib = __builtin_amdgcn_readlane(cidx, l);
                        // victim = lane holding current min (== tau, exact)
                        const unsigned long long vm = __ballot(vlist[r] == tau[r]);
                        const int vml = __ffsll(vm) - 1;
                        if (lane == vml) { vlist[r] = pb; ilist[r] = ib; }
                        // refresh tau = min over the 16 (upper lanes are +inf)
                        float mn = vlist[r];
#pragma unroll
                        for (int off = 32; off > 0; off >>= 1)
                            mn = fminf(mn, __shfl_xor(mn, off, 64));
                        tau[r] = __uint_as_float(
                            __builtin_amdgcn_readfirstlane(__float_as_uint(mn)));
                        m[r] &= (m[r] - 1);                   // drop processed lane
                        m[r] &= __ballot(p[r] > tau[r]);      // re-prune, tighter tau
                    }
                }
            }
        }
    }

    if (lane < K_NBR) {
#pragma unroll
        for (int r = 0; r < 4; ++r)
            knn[(row0 + r) * K_NBR + lane] = ilist[r];
    }
}

// ---------------- edge-feature MLP: 4 points per wave, lane = out feature ---
// h1 buffer is per-wave private; wave-lockstep execution + compiler LDS alias
// ordering make __syncthreads unnecessary (waves never convoy).
__global__ __launch_bounds__(256) void mlp_kernel(const float4* __restrict__ x4,
                                                  const int* __restrict__ knn,
                                                  const float* __restrict__ W1,
                                                  const float* __restrict__ b1,
                                                  const float* __restrict__ W2,
                                                  const float* __restrict__ b2,
                                                  float* __restrict__ out) {
    __shared__ __align__(16) float h1s[4][K_NBR][H_DIM];  // 16 KB, per-wave slices
    const int lane = threadIdx.x & 63;
    const int wave = threadIdx.x >> 6;
    const int p0   = (blockIdx.x * 4 + wave) * MLP_PW;

    // per-lane weight rows in registers, loaded ONCE per wave
    float w1r[8];
#pragma unroll
    for (int c = 0; c < 8; ++c) w1r[c] = W1[lane * 8 + c];
    const float b1r = b1[lane];
    const float b2r = b2[lane];
    float w2r[64];
#pragma unroll
    for (int j = 0; j < 64; ++j) w2r[j] = W2[lane * 64 + j];

    for (int pp = 0; pp < MLP_PW; ++pp) {
        const int p = p0 + pp;
        const float4 xi = x4[p];

        // layer 1 for all 16 neighbors (lane = hidden feature)
        for (int k = 0; k < K_NBR; ++k) {
            const int nb = knn[p * K_NBR + k];
            const float4 xj = x4[nb];
            float h = b1r;
            h = fmaf(w1r[0], xj.x - xi.x, h);
            h = fmaf(w1r[1], xj.y - xi.y, h);
            h = fmaf(w1r[2], xj.z - xi.z, h);
            h = fmaf(w1r[3], xj.w - xi.w, h);
            h = fmaf(w1r[4], xi.x, h);
            h = fmaf(w1r[5], xi.y, h);
            h = fmaf(w1r[6], xi.z, h);
            h = fmaf(w1r[7], xi.w, h);
            h1s[wave][k][lane] = fmaxf(h, 0.0f);
        }

        // layer 2 (lane = out feature): broadcast b128 LDS reads
        float acc[K_NBR];
#pragma unroll
        for (int k = 0; k < K_NBR; ++k) acc[k] = b2r;

#pragma unroll
        for (int h4 = 0; h4 < H_DIM / 4; ++h4) {
#pragma unroll
            for (int k = 0; k < K_NBR; ++k) {
                const float4 hv = *(const float4*)&h1s[wave][k][h4 * 4];
                acc[k] = fmaf(w2r[4 * h4 + 0], hv.x, acc[k]);
                acc[k] = fmaf(w2r[4 * h4 + 1], hv.y, acc[k]);
                acc[k] = fmaf(w2r[4 * h4 + 2], hv.z, acc[k]);
                acc[k] = fmaf(w2r[4 * h4 + 3], hv.w, acc[k]);
            }
        }

        float s = 0.0f;
#pragma unroll
        for (int k = 0; k < K_NBR; ++k) s += fmaxf(acc[k], 0.0f);
        out[p * H_DIM + lane] = s * (1.0f / 16.0f);
    }
}

extern "C" void kernel_launch(void* const* d_in, const int* in_sizes, int n_in,
                              void* d_out, int out_size, void* d_ws, size_t ws_size,
                              hipStream_t stream) {
    (void)in_sizes; (void)n_in; (void)out_size; (void)ws_size;
    const float* x  = (const float*)d_in[0];
    const float* W1 = (const float*)d_in[1];
    const float* b1 = (const float*)d_in[2];
    const float* W2 = (const float*)d_in[3];
    const float* b2 = (const float*)d_in[4];
    float* out = (float*)d_out;

    float* xx  = (float*)d_ws;                                  // N floats
    int*   knn = (int*)((char*)d_ws + N_PTS * sizeof(float));   // N*K ints

    const float4* x4 = (const float4*)x;

    xx_kernel <<<N_PTS / 256, 256, 0, stream>>>(x4, xx);
    knn_kernel<<<N_PTS / 16,  256, 0, stream>>>(x4, xx, knn);
    mlp_kernel<<<N_PTS / 16,  256, 0, stream>>>(x4, knn, W1, b1, W2, b2, out);
}

// Round 5
// 314.409 us; speedup vs baseline: 1.1695x; 1.1695x over previous
//
#include <hip/hip_runtime.h>
#include <math.h>

#define N_PTS 16384
#define K_NBR 16
#define H_DIM 64
#define TS    1024   // kNN LDS tile (points)
#define CAP   192    // per-row candidate buffer (entries)
#define MLP_PW 4     // points per wave in mlp

typedef unsigned long long u64;

// prefix count of set bits of m strictly below my lane
__device__ __forceinline__ int prefix_lt(u64 m) {
    return __builtin_amdgcn_mbcnt_hi((unsigned)(m >> 32),
           __builtin_amdgcn_mbcnt_lo((unsigned)m, 0));
}
// key = (order-preserving float bits, ~idx): sorts by value desc then idx asc
__device__ __forceinline__ u64 mkkey(unsigned vbits, unsigned idx) {
    unsigned of = vbits ^ (unsigned)(((int)vbits >> 31) | 0x80000000);
    return ((u64)of << 32) | (unsigned)(~idx);
}
__device__ __forceinline__ float keyval(u64 k) {
    unsigned of = (unsigned)(k >> 32);
    unsigned vb = (of & 0x80000000u) ? (of ^ 0x80000000u) : ~of;
    return __uint_as_float(vb);
}
__device__ __forceinline__ unsigned keyidx(u64 k) { return ~(unsigned)k; }

// 64-lane bitonic ascending sort of keys; returns 16th-largest (lane 48)
__device__ __forceinline__ u64 wave_key16(u64 v, int lane) {
#pragma unroll
    for (int k = 2; k <= 64; k <<= 1) {
#pragma unroll
        for (int j = k >> 1; j > 0; j >>= 1) {
            u64 o = __shfl_xor((unsigned long long)v, j, 64);
            bool ddd   = ((lane & k) == 0);
            bool lower = ((lane & j) == 0);
            u64 mn = (v < o) ? v : o;
            u64 mx = (v < o) ? o : v;
            v = (ddd == lower) ? mn : mx;
        }
    }
    u64 r = ((u64)__builtin_amdgcn_readlane((unsigned)(v >> 32), 48) << 32)
          |  (unsigned)__builtin_amdgcn_readlane((unsigned)v, 48);
    return r;
}

// raise tau to 16th-largest-of-lane-max-keys, drop entries below; nc <= 48
__device__ __forceinline__ int wave_compact(uint2* buf, int cnt, float* tau,
                                            int lane) {
    u64 lm = 0;
    for (int s = lane; s < cnt; s += 64) {
        uint2 e = buf[s];
        u64 k = mkkey(e.x, e.y);
        lm = (k > lm) ? k : lm;
    }
    const u64 tk = wave_key16(lm, lane);
    int nc = 0;
    for (int s0 = 0; s0 < cnt; s0 += 64) {
        const int s = s0 + lane;
        uint2 e = make_uint2(0u, 0u);
        bool keep = false;
        if (s < cnt) {
            e = buf[s];
            keep = (mkkey(e.x, e.y) >= tk);
        }
        const u64 km = __ballot(keep);
        const int pre = prefix_lt(km);
        if (keep) buf[nc + pre] = e;   // write idx <= read idx: in-place safe
        nc += (int)__popcll(km);
    }
    *tau = keyval(tk);                 // tau <= 16th of seen <= final 16th
    return nc;
}

// ---------------- xx[i] = sum(x[i]^2), mimicking numpy squares-then-sum ----
__global__ __launch_bounds__(256) void xx_kernel(const float4* __restrict__ x4,
                                                 float* __restrict__ xx) {
    int i = blockIdx.x * 256 + threadIdx.x;
    float4 v = x4[i];
    {
#pragma clang fp contract(off)
        float s0 = v.x * v.x;
        float s1 = v.y * v.y;
        float s2 = v.z * v.z;
        float s3 = v.w * v.w;
        xx[i] = ((s0 + s1) + s2) + s3;
    }
}

// ---------------- brute-force kNN: filter-append-compact, 1 row per wave ---
__global__ __launch_bounds__(256) void knn_kernel(const float4* __restrict__ x4,
                                                  const float* __restrict__ xx,
                                                  int* __restrict__ knn) {
    __shared__ float4 xs[TS];              // 16 KB
    __shared__ float  nxxs[TS];            // 4 KB
    __shared__ uint2  buf[4][CAP];         // 6 KB  (total 26 KB -> 6 blk/CU)
    const int lane = threadIdx.x & 63;
    const int wave = threadIdx.x >> 6;
    const int row  = blockIdx.x * 4 + wave;
    uint2* mybuf = buf[wave];

    const float4 t0 = x4[row];
    const float4 y  = make_float4(2.0f * t0.x, 2.0f * t0.y,
                                  2.0f * t0.z, 2.0f * t0.w);
    const float nxxi = -xx[row];

    float tau = -INFINITY;
    int   cnt = 0;

    for (int t = 0; t < N_PTS / TS; ++t) {
        const int base = t * TS;
        __syncthreads();
        for (int i = threadIdx.x; i < TS; i += 256) {
            xs[i]   = x4[base + i];
            nxxs[i] = -xx[base + i];
        }
        __syncthreads();

        for (int c = lane; c < TS; c += 64) {
            const float4 xj = xs[c];
            const float p = fmaf(y.x, xj.x, fmaf(y.y, xj.y,
                             fmaf(y.z, xj.z, fmaf(y.w, xj.w, nxxs[c] + nxxi))));
            const u64 m = __ballot(p > tau);
            if (m) {                                   // wave-uniform, rare late
                const int pre = prefix_lt(m);
                if (p > tau)
                    mybuf[cnt + pre] =
                        make_uint2(__float_as_uint(p), (unsigned)(base + c));
                cnt += (int)__popcll(m);
                if (cnt > CAP - 64)                    // keep 64 slots free
                    cnt = wave_compact(mybuf, cnt, &tau, lane);
            }
        }
    }

    // final exact top-16 by key (value desc, idx asc) over <=192 entries
    u64 key[3];
#pragma unroll
    for (int q = 0; q < 3; ++q) {
        const int s = lane + q * 64;
        key[q] = 0;                                    // sentinel < any real key
        if (s < cnt) {
            const uint2 e = mybuf[s];
            key[q] = mkkey(e.x, e.y);
        }
    }
    int myidx = -1;
    for (int r = 0; r < K_NBR; ++r) {
        u64 b = key[0];
        b = (key[1] > b) ? key[1] : b;
        b = (key[2] > b) ? key[2] : b;
        u64 w = b;
#pragma unroll
        for (int off = 32; off > 0; off >>= 1) {
            const u64 o = __shfl_xor((unsigned long long)w, off, 64);
            w = (o > w) ? o : w;
        }
#pragma unroll
        for (int q = 0; q < 3; ++q)
            if (key[q] == w) key[q] = 0;               // unique winner retires
        if (lane == r) myidx = (int)keyidx(w);
    }
    if (lane < K_NBR) knn[row * K_NBR + lane] = myidx;
}

// ---------------- edge-feature MLP: 4 points per wave, lane = out feature ---
__global__ __launch_bounds__(256) void mlp_kernel(const float4* __restrict__ x4,
                                                  const int* __restrict__ knn,
                                                  const float* __restrict__ W1,
                                                  const float* __restrict__ b1,
                                                  const float* __restrict__ W2,
                                                  const float* __restrict__ b2,
                                                  float* __restrict__ out) {
    __shared__ __align__(16) float h1s[4][K_NBR][H_DIM];  // 16 KB, per-wave
    const int lane = threadIdx.x & 63;
    const int wave = threadIdx.x >> 6;
    const int p0   = (blockIdx.x * 4 + wave) * MLP_PW;

    float w1r[8];
#pragma unroll
    for (int c = 0; c < 8; ++c) w1r[c] = W1[lane * 8 + c];
    const float b1r = b1[lane];
    const float b2r = b2[lane];
    float w2r[64];
#pragma unroll
    for (int j = 0; j < 64; ++j) w2r[j] = W2[lane * 64 + j];

    for (int pp = 0; pp < MLP_PW; ++pp) {
        const int p = p0 + pp;
        const float4 xi = x4[p];

        for (int k = 0; k < K_NBR; ++k) {
            const int nb = knn[p * K_NBR + k];
            const float4 xj = x4[nb];
            float h = b1r;
            h = fmaf(w1r[0], xj.x - xi.x, h);
            h = fmaf(w1r[1], xj.y - xi.y, h);
            h = fmaf(w1r[2], xj.z - xi.z, h);
            h = fmaf(w1r[3], xj.w - xi.w, h);
            h = fmaf(w1r[4], xi.x, h);
            h = fmaf(w1r[5], xi.y, h);
            h = fmaf(w1r[6], xi.z, h);
            h = fmaf(w1r[7], xi.w, h);
            h1s[wave][k][lane] = fmaxf(h, 0.0f);
        }

        float acc[K_NBR];
#pragma unroll
        for (int k = 0; k < K_NBR; ++k) acc[k] = b2r;

#pragma unroll
        for (int h4 = 0; h4 < H_DIM / 4; ++h4) {
#pragma unroll
            for (int k = 0; k < K_NBR; ++k) {
                const float4 hv = *(const float4*)&h1s[wave][k][h4 * 4];
                acc[k] = fmaf(w2r[4 * h4 + 0], hv.x, acc[k]);
                acc[k] = fmaf(w2r[4 * h4 + 1], hv.y, acc[k]);
                acc[k] = fmaf(w2r[4 * h4 + 2], hv.z, acc[k]);
                acc[k] = fmaf(w2r[4 * h4 + 3], hv.w, acc[k]);
            }
        }

        float s = 0.0f;
#pragma unroll
        for (int k = 0; k < K_NBR; ++k) s += fmaxf(acc[k], 0.0f);
        out[p * H_DIM + lane] = s * (1.0f / 16.0f);
    }
}

extern "C" void kernel_launch(void* const* d_in, const int* in_sizes, int n_in,
                              void* d_out, int out_size, void* d_ws, size_t ws_size,
                              hipStream_t stream) {
    (void)in_sizes; (void)n_in; (void)out_size; (void)ws_size;
    const float* x  = (const float*)d_in[0];
    const float* W1 = (const float*)d_in[1];
    const float* b1 = (const float*)d_in[2];
    const float* W2 = (const float*)d_in[3];
    const float* b2 = (const float*)d_in[4];
    float* out = (float*)d_out;

    float* xx  = (float*)d_ws;                                  // N floats
    int*   knn = (int*)((char*)d_ws + N_PTS * sizeof(float));   // N*K ints

    const float4* x4 = (const float4*)x;

    xx_kernel <<<N_PTS / 256, 256, 0, stream>>>(x4, xx);
    knn_kernel<<<N_PTS / 4,   256, 0, stream>>>(x4, xx, knn);
    mlp_kernel<<<N_PTS / 16,  256, 0, stream>>>(x4, knn, W1, b1, W2, b2, out);
}

// Round 6
// 281.206 us; speedup vs baseline: 1.3075x; 1.1181x over previous
//
#include <hip/hip_runtime.h>
#include <math.h>

#define N_PTS 16384
#define K_NBR 16
#define H_DIM 64
#define TS    1024   // kNN LDS tile (points)
#define CAP   128    // per-row candidate buffer (entries)
#define RPW   4      // kNN rows per wave
#define MLP_PW 2     // points per wave in mlp

typedef unsigned long long u64;

// prefix count of set bits of m strictly below my lane
__device__ __forceinline__ int prefix_lt(u64 m) {
    return __builtin_amdgcn_mbcnt_hi((unsigned)(m >> 32),
           __builtin_amdgcn_mbcnt_lo((unsigned)m, 0));
}
// key = (order-preserving float bits, ~idx): sorts by value desc then idx asc
__device__ __forceinline__ u64 mkkey(unsigned vbits, unsigned idx) {
    unsigned of = vbits ^ (unsigned)(((int)vbits >> 31) | 0x80000000);
    return ((u64)of << 32) | (unsigned)(~idx);
}
__device__ __forceinline__ float keyval(u64 k) {
    unsigned of = (unsigned)(k >> 32);
    unsigned vb = (of & 0x80000000u) ? (of ^ 0x80000000u) : ~of;
    return __uint_as_float(vb);
}
__device__ __forceinline__ unsigned keyidx(u64 k) { return ~(unsigned)k; }

// 64-lane bitonic ascending sort of keys; returns 16th-largest (lane 48)
__device__ __forceinline__ u64 wave_key16(u64 v, int lane) {
#pragma unroll
    for (int k = 2; k <= 64; k <<= 1) {
#pragma unroll
        for (int j = k >> 1; j > 0; j >>= 1) {
            u64 o = __shfl_xor((unsigned long long)v, j, 64);
            bool ddd   = ((lane & k) == 0);
            bool lower = ((lane & j) == 0);
            u64 mn = (v < o) ? v : o;
            u64 mx = (v < o) ? o : v;
            v = (ddd == lower) ? mn : mx;
        }
    }
    u64 r = ((u64)__builtin_amdgcn_readlane((unsigned)(v >> 32), 48) << 32)
          |  (unsigned)__builtin_amdgcn_readlane((unsigned)v, 48);
    return r;
}

// raise tau to 16th-largest-of-lane-max-keys, drop entries below; nc <= 32
__device__ __forceinline__ int wave_compact(uint2* buf, int cnt, float* tau,
                                            int lane) {
    u64 lm = 0;
    for (int s = lane; s < cnt; s += 64) {
        uint2 e = buf[s];
        u64 k = mkkey(e.x, e.y);
        lm = (k > lm) ? k : lm;
    }
    const u64 tk = wave_key16(lm, lane);
    int nc = 0;
    for (int s0 = 0; s0 < cnt; s0 += 64) {
        const int s = s0 + lane;
        uint2 e = make_uint2(0u, 0u);
        bool keep = false;
        if (s < cnt) {
            e = buf[s];
            keep = (mkkey(e.x, e.y) >= tk);
        }
        const u64 km = __ballot(keep);
        const int pre = prefix_lt(km);
        if (keep) buf[nc + pre] = e;   // write idx <= read idx: in-place safe
        nc += (int)__popcll(km);
    }
    *tau = keyval(tk);                 // tau <= 16th of seen <= final 16th
    return nc;
}

// ---------------- xx[i] = sum(x[i]^2), mimicking numpy squares-then-sum ----
__global__ __launch_bounds__(256) void xx_kernel(const float4* __restrict__ x4,
                                                 float* __restrict__ xx) {
    int i = blockIdx.x * 256 + threadIdx.x;
    float4 v = x4[i];
    {
#pragma clang fp contract(off)
        float s0 = v.x * v.x;
        float s1 = v.y * v.y;
        float s2 = v.z * v.z;
        float s3 = v.w * v.w;
        xx[i] = ((s0 + s1) + s2) + s3;
    }
}

// ---------------- brute-force kNN: 4 rows/wave, filter-append-compact ------
__global__ __launch_bounds__(256) void knn_kernel(const float4* __restrict__ x4,
                                                  const float* __restrict__ xx,
                                                  int* __restrict__ knn) {
    __shared__ float4 xs[TS];              // 16 KB
    __shared__ float  nxxs[TS];            // 4 KB
    __shared__ uint2  buf[16][CAP];        // 16 KB  (total 36 KB -> 4 blk/CU)
    const int lane = threadIdx.x & 63;
    const int wave = threadIdx.x >> 6;
    const int row0 = blockIdx.x * 16 + wave * RPW;

    float4 y[RPW];
    float  nxxi[RPW];
#pragma unroll
    for (int r = 0; r < RPW; ++r) {
        const float4 t0 = x4[row0 + r];
        y[r] = make_float4(2.0f * t0.x, 2.0f * t0.y, 2.0f * t0.z, 2.0f * t0.w);
        nxxi[r] = -xx[row0 + r];
    }

    float tau[RPW];
    int   cnt[RPW];
#pragma unroll
    for (int r = 0; r < RPW; ++r) { tau[r] = -INFINITY; cnt[r] = 0; }

    for (int t = 0; t < N_PTS / TS; ++t) {
        const int base = t * TS;
        __syncthreads();
        for (int i = threadIdx.x; i < TS; i += 256) {
            xs[i]   = x4[base + i];
            nxxs[i] = -xx[base + i];
        }
        __syncthreads();

        for (int c = lane; c < TS; c += 64) {
            const float4 xj = xs[c];
            const float  nx = nxxs[c];
            float p[RPW];
            u64   m[RPW];
#pragma unroll
            for (int r = 0; r < RPW; ++r) {
                p[r] = fmaf(y[r].x, xj.x, fmaf(y[r].y, xj.y,
                        fmaf(y[r].z, xj.z, fmaf(y[r].w, xj.w, nx + nxxi[r]))));
                m[r] = __ballot(p[r] > tau[r]);
            }
            if (m[0] | m[1] | m[2] | m[3]) {     // wave-uniform, mostly early
#pragma unroll
                for (int r = 0; r < RPW; ++r) {
                    if (m[r]) {
                        const int pre = prefix_lt(m[r]);
                        if (p[r] > tau[r])
                            buf[wave * RPW + r][cnt[r] + pre] =
                                make_uint2(__float_as_uint(p[r]),
                                           (unsigned)(base + c));
                        cnt[r] += (int)__popcll(m[r]);
                        if (cnt[r] > CAP - 64)   // keep 64 slots free
                            cnt[r] = wave_compact(&buf[wave * RPW + r][0],
                                                  cnt[r], &tau[r], lane);
                    }
                }
            }
        }
    }

    // final exact top-16 per row (value desc, idx asc) over <=128 entries
#pragma unroll
    for (int r = 0; r < RPW; ++r) {
        u64 key[2];
#pragma unroll
        for (int q = 0; q < 2; ++q) {
            const int s = lane + q * 64;
            key[q] = 0;                          // sentinel < any real key
            if (s < cnt[r]) {
                const uint2 e = buf[wave * RPW + r][s];
                key[q] = mkkey(e.x, e.y);
            }
        }
        int myidx = -1;
        for (int rr = 0; rr < K_NBR; ++rr) {
            u64 w = (key[1] > key[0]) ? key[1] : key[0];
#pragma unroll
            for (int off = 32; off > 0; off >>= 1) {
                const u64 o = __shfl_xor((unsigned long long)w, off, 64);
                w = (o > w) ? o : w;
            }
#pragma unroll
            for (int q = 0; q < 2; ++q)
                if (key[q] == w) key[q] = 0;     // unique winner retires
            if (lane == rr) myidx = (int)keyidx(w);
        }
        if (lane < K_NBR) knn[(row0 + r) * K_NBR + lane] = myidx;
    }
}

// ---------------- edge-feature MLP: 2 points/wave, W2 in LDS ---------------
// w2s[h4][g] = W2[g][4h4..4h4+3]: lane-stride 16B reads = contiguous 1 KB,
// conflict-free. Removes the 64-VGPR w2 register file -> higher occupancy.
__global__ __launch_bounds__(256) void mlp_kernel(const float4* __restrict__ x4,
                                                  const int* __restrict__ knn,
                                                  const float4* __restrict__ W2f4,
                                                  const float* __restrict__ W1,
                                                  const float* __restrict__ b1,
                                                  const float* __restrict__ b2,
                                                  float* __restrict__ out) {
    __shared__ __align__(16) float4 w2s[16][64];          // 16 KB
    __shared__ __align__(16) float  h1s[4][K_NBR][H_DIM]; // 16 KB, per-wave
    const int lane = threadIdx.x & 63;
    const int wave = threadIdx.x >> 6;
    const int p0   = (blockIdx.x * 4 + wave) * MLP_PW;

    for (int q = threadIdx.x; q < 1024; q += 256)
        w2s[q & 15][q >> 4] = W2f4[q];        // W2 row-major f4: [g][h4]
    __syncthreads();

    float w1r[8];
#pragma unroll
    for (int c = 0; c < 8; ++c) w1r[c] = W1[lane * 8 + c];
    const float b1r = b1[lane];
    const float b2r = b2[lane];

    for (int pp = 0; pp < MLP_PW; ++pp) {
        const int p = p0 + pp;
        const float4 xi = x4[p];

        // layer 1 (lane = hidden feature)
        for (int k = 0; k < K_NBR; ++k) {
            const int nb = knn[p * K_NBR + k];
            const float4 xj = x4[nb];
            float h = b1r;
            h = fmaf(w1r[0], xj.x - xi.x, h);
            h = fmaf(w1r[1], xj.y - xi.y, h);
            h = fmaf(w1r[2], xj.z - xi.z, h);
            h = fmaf(w1r[3], xj.w - xi.w, h);
            h = fmaf(w1r[4], xi.x, h);
            h = fmaf(w1r[5], xi.y, h);
            h = fmaf(w1r[6], xi.z, h);
            h = fmaf(w1r[7], xi.w, h);
            h1s[wave][k][lane] = fmaxf(h, 0.0f);
        }

        // layer 2 (lane = out feature g)
        float acc[K_NBR];
#pragma unroll
        for (int k = 0; k < K_NBR; ++k) acc[k] = b2r;

#pragma unroll
        for (int h4 = 0; h4 < H_DIM / 4; ++h4) {
            const float4 w4 = w2s[h4][lane];
#pragma unroll
            for (int k = 0; k < K_NBR; ++k) {
                const float4 hv = *(const float4*)&h1s[wave][k][h4 * 4];
                acc[k] = fmaf(w4.x, hv.x, acc[k]);
                acc[k] = fmaf(w4.y, hv.y, acc[k]);
                acc[k] = fmaf(w4.z, hv.z, acc[k]);
                acc[k] = fmaf(w4.w, hv.w, acc[k]);
            }
        }

        float s = 0.0f;
#pragma unroll
        for (int k = 0; k < K_NBR; ++k) s += fmaxf(acc[k], 0.0f);
        out[p * H_DIM + lane] = s * (1.0f / 16.0f);
    }
}

extern "C" void kernel_launch(void* const* d_in, const int* in_sizes, int n_in,
                              void* d_out, int out_size, void* d_ws, size_t ws_size,
                              hipStream_t stream) {
    (void)in_sizes; (void)n_in; (void)out_size; (void)ws_size;
    const float* x  = (const float*)d_in[0];
    const float* W1 = (const float*)d_in[1];
    const float* b1 = (const float*)d_in[2];
    const float* W2 = (const float*)d_in[3];
    const float* b2 = (const float*)d_in[4];
    float* out = (float*)d_out;

    float* xx  = (float*)d_ws;                                  // N floats
    int*   knn = (int*)((char*)d_ws + N_PTS * sizeof(float));   // N*K ints

    const float4* x4 = (const float4*)x;

    xx_kernel <<<N_PTS / 256, 256, 0, stream>>>(x4, xx);
    knn_kernel<<<N_PTS / 16,  256, 0, stream>>>(x4, xx, knn);
    mlp_kernel<<<N_PTS / (4 * MLP_PW), 256, 0, stream>>>(
        x4, knn, (const float4*)W2, W1, b1, b2, out);
}

// Round 7
// 271.266 us; speedup vs baseline: 1.3554x; 1.0366x over previous
//
#include <hip/hip_runtime.h>
#include <math.h>

#define N_PTS 16384
#define K_NBR 16
#define H_DIM 64
#define TS    1024   // kNN LDS tile (points)
#define CAP   96     // per-row candidate buffer (entries)
#define RPW   4      // kNN rows per wave

typedef unsigned long long u64;

// prefix count of set bits of m strictly below my lane
__device__ __forceinline__ int prefix_lt(u64 m) {
    return __builtin_amdgcn_mbcnt_hi((unsigned)(m >> 32),
           __builtin_amdgcn_mbcnt_lo((unsigned)m, 0));
}
// key = (order-preserving float bits, ~idx): sorts by value desc then idx asc
__device__ __forceinline__ u64 mkkey(unsigned vbits, unsigned idx) {
    unsigned of = vbits ^ (unsigned)(((int)vbits >> 31) | 0x80000000);
    return ((u64)of << 32) | (unsigned)(~idx);
}
__device__ __forceinline__ unsigned keyidx(u64 k) { return ~(unsigned)k; }

__device__ __forceinline__ float readlane_f(float v, int l) {
    return __uint_as_float(__builtin_amdgcn_readlane(__float_as_uint(v), l));
}

// 64-lane bitonic ascending sort, float
__device__ __forceinline__ float wave_sort_f32(float v, int lane) {
#pragma unroll
    for (int k = 2; k <= 64; k <<= 1) {
#pragma unroll
        for (int j = k >> 1; j > 0; j >>= 1) {
            float o = __shfl_xor(v, j, 64);
            bool keep_min = (((lane & k) == 0) == ((lane & j) == 0));
            v = keep_min ? fminf(v, o) : fmaxf(v, o);
        }
    }
    return v;
}
// 64-lane bitonic ascending sort, u64 keys
__device__ __forceinline__ u64 wave_sort_u64(u64 v, int lane) {
#pragma unroll
    for (int k = 2; k <= 64; k <<= 1) {
#pragma unroll
        for (int j = k >> 1; j > 0; j >>= 1) {
            u64 o = __shfl_xor((unsigned long long)v, j, 64);
            bool keep_min = (((lane & k) == 0) == ((lane & j) == 0));
            u64 mn = (v < o) ? v : o;
            u64 mx = (v < o) ? o : v;
            v = keep_min ? mn : mx;
        }
    }
    return v;
}

// raise tau to 16th-largest of per-lane max VALUES, drop entries below.
// Exact: tau <= 16th-largest value seen; >=-keep retains all boundary ties
// (which have lower indices than any future candidate). Survivors <= 32.
__device__ __forceinline__ int wave_compact(uint2* buf, int cnt, float* tau,
                                            int lane) {
    float lm = -INFINITY;
    for (int s = lane; s < cnt; s += 64)
        lm = fmaxf(lm, __uint_as_float(buf[s].x));
    const float tv = readlane_f(wave_sort_f32(lm, lane), 48);
    int nc = 0;
    for (int s0 = 0; s0 < cnt; s0 += 64) {
        const int s = s0 + lane;
        uint2 e = make_uint2(0u, 0u);
        bool keep = false;
        if (s < cnt) { e = buf[s]; keep = (__uint_as_float(e.x) >= tv); }
        const u64 km = __ballot(keep);
        if (keep) buf[nc + prefix_lt(km)] = e;  // write idx <= read idx: safe
        nc += (int)__popcll(km);
    }
    *tau = tv;
    return nc;
}

// ---------------- xx[i] = sum(x[i]^2), mimicking numpy squares-then-sum ----
__global__ __launch_bounds__(256) void xx_kernel(const float4* __restrict__ x4,
                                                 float* __restrict__ xx) {
    int i = blockIdx.x * 256 + threadIdx.x;
    float4 v = x4[i];
    {
#pragma clang fp contract(off)
        float s0 = v.x * v.x;
        float s1 = v.y * v.y;
        float s2 = v.z * v.z;
        float s3 = v.w * v.w;
        xx[i] = ((s0 + s1) + s2) + s3;
    }
}

// ---------------- brute-force kNN: 4 rows/wave, seed + filter-append-compact
__global__ __launch_bounds__(256) void knn_kernel(const float4* __restrict__ x4,
                                                  const float* __restrict__ xx,
                                                  int* __restrict__ knn) {
    __shared__ float4 xs[TS];              // 16 KB
    __shared__ float  nxxs[TS];            // 4 KB
    __shared__ uint2  buf[16][CAP];        // 12 KB  (32 KB -> 5 blk/CU)
    const int lane = threadIdx.x & 63;
    const int wave = threadIdx.x >> 6;
    const int row0 = blockIdx.x * 16 + wave * RPW;

    float4 y[RPW];
    float  nxxi[RPW];
#pragma unroll
    for (int r = 0; r < RPW; ++r) {
        const float4 t0 = x4[row0 + r];
        y[r] = make_float4(2.0f * t0.x, 2.0f * t0.y, 2.0f * t0.z, 2.0f * t0.w);
        nxxi[r] = -xx[row0 + r];
    }

    float tau[RPW];
    int   cnt[RPW];
#pragma unroll
    for (int r = 0; r < RPW; ++r) { tau[r] = -INFINITY; cnt[r] = 0; }

    for (int t = 0; t < N_PTS / TS; ++t) {
        const int base = t * TS;
        __syncthreads();
        for (int i = threadIdx.x; i < TS; i += 256) {
            xs[i]   = x4[base + i];
            nxxs[i] = -xx[base + i];
        }
        __syncthreads();

        int cstart = lane;
        if (t == 0) {
            // seed: exact 16th-largest of first 64 candidates per row
            const float4 xj = xs[lane];
            const float  nx = nxxs[lane];
#pragma unroll
            for (int r = 0; r < RPW; ++r) {
                const float p = fmaf(y[r].x, xj.x, fmaf(y[r].y, xj.y,
                                 fmaf(y[r].z, xj.z,
                                 fmaf(y[r].w, xj.w, nx + nxxi[r]))));
                tau[r] = readlane_f(wave_sort_f32(p, lane), 48);
                const u64 m = __ballot(p >= tau[r]);   // >= keeps boundary ties
                if (p >= tau[r])
                    buf[wave * RPW + r][prefix_lt(m)] =
                        make_uint2(__float_as_uint(p), (unsigned)lane);
                cnt[r] = (int)__popcll(m);
                if (cnt[r] > CAP - 64)                 // pathological ties only
                    cnt[r] = wave_compact(&buf[wave * RPW + r][0],
                                          cnt[r], &tau[r], lane);
            }
            cstart = lane + 64;
        }

        for (int c = cstart; c < TS; c += 64) {
            const float4 xj = xs[c];
            const float  nx = nxxs[c];
            float p[RPW];
            u64   m[RPW];
#pragma unroll
            for (int r = 0; r < RPW; ++r) {
                p[r] = fmaf(y[r].x, xj.x, fmaf(y[r].y, xj.y,
                        fmaf(y[r].z, xj.z, fmaf(y[r].w, xj.w, nx + nxxi[r]))));
                m[r] = __ballot(p[r] > tau[r]);
            }
            if (m[0] | m[1] | m[2] | m[3]) {     // wave-uniform, rare post-seed
#pragma unroll
                for (int r = 0; r < RPW; ++r) {
                    if (m[r]) {
                        const int pre = prefix_lt(m[r]);
                        if (p[r] > tau[r])
                            buf[wave * RPW + r][cnt[r] + pre] =
                                make_uint2(__float_as_uint(p[r]),
                                           (unsigned)(base + c));
                        cnt[r] += (int)__popcll(m[r]);
                        if (cnt[r] > CAP - 64)   // keep 64 slots free
                            cnt[r] = wave_compact(&buf[wave * RPW + r][0],
                                                  cnt[r], &tau[r], lane);
                    }
                }
            }
        }
    }

    // final: compact to <=32, one u64-key bitonic sort, lanes 48..63 = top-16
#pragma unroll
    for (int r = 0; r < RPW; ++r) {
        uint2* mybuf = &buf[wave * RPW + r][0];
        const int c2 = wave_compact(mybuf, cnt[r], &tau[r], lane);
        u64 key = 0;                               // sentinel < any real key
        if (lane < c2) {
            const uint2 e = mybuf[lane];
            key = mkkey(e.x, e.y);
        }
        key = wave_sort_u64(key, lane);
        if (lane >= 48)
            knn[(row0 + r) * K_NBR + (lane - 48)] = (int)keyidx(key);
    }
}

// ---------------- edge-feature MLP: lane=(kq,g'), wide LDS reads -----------
// Layer1: lane = hidden h, writes h1s[k][h] (row stride 68: 2-way, free).
// Layer2: lane kq=lane>>4 handles k=kq*4..+3; g'=lane&15 handles g=g'+16*gq.
// h1 reads: 4-distinct-address b128 (64/pt vs 256 broadcast before).
__global__ __launch_bounds__(256) void mlp_kernel(const float4* __restrict__ x4,
                                                  const int* __restrict__ knn,
                                                  const float4* __restrict__ W2f4,
                                                  const float* __restrict__ W1,
                                                  const float* __restrict__ b1,
                                                  const float* __restrict__ b2,
                                                  float* __restrict__ out) {
    __shared__ __align__(16) float4 w2s[16][64];     // 16 KB, h4-major
    __shared__ __align__(16) float  h1s[4][16][68];  // 17 KB, per-wave, padded
    const int lane = threadIdx.x & 63;
    const int wave = threadIdx.x >> 6;
    const int kq   = lane >> 4;
    const int gp   = lane & 15;
    const int p0   = (blockIdx.x * 4 + wave) * 4;    // 4 points per wave

    for (int q = threadIdx.x; q < 1024; q += 256)
        w2s[q & 15][q >> 4] = W2f4[q];               // w2s[h4][g]
    __syncthreads();

    float w1r[8];
#pragma unroll
    for (int c = 0; c < 8; ++c) w1r[c] = W1[lane * 8 + c];
    const float b1r = b1[lane];
    float b2r[4];
#pragma unroll
    for (int gq = 0; gq < 4; ++gq) b2r[gq] = b2[gq * 16 + gp];

    for (int pp = 0; pp < 4; ++pp) {
        const int p = p0 + pp;
        const float4 xi = x4[p];

        // layer 1 (lane = hidden feature h)
        for (int k = 0; k < K_NBR; ++k) {
            const int nb = knn[p * K_NBR + k];
            const float4 xj = x4[nb];
            float h = b1r;
            h = fmaf(w1r[0], xj.x - xi.x, h);
            h = fmaf(w1r[1], xj.y - xi.y, h);
            h = fmaf(w1r[2], xj.z - xi.z, h);
            h = fmaf(w1r[3], xj.w - xi.w, h);
            h = fmaf(w1r[4], xi.x, h);
            h = fmaf(w1r[5], xi.y, h);
            h = fmaf(w1r[6], xi.z, h);
            h = fmaf(w1r[7], xi.w, h);
            h1s[wave][k][lane] = fmaxf(h, 0.0f);
        }
        // wave-private LDS: in-wave lgkmcnt ordering suffices, no barrier

        // layer 2: acc[kk][gq] = full 64-h dot for (k=kq*4+kk, g=gq*16+gp)
        float acc[4][4];
#pragma unroll
        for (int kk = 0; kk < 4; ++kk)
#pragma unroll
            for (int gq = 0; gq < 4; ++gq) acc[kk][gq] = b2r[gq];

#pragma unroll
        for (int h4 = 0; h4 < 16; ++h4) {
            float4 w4[4];
#pragma unroll
            for (int gq = 0; gq < 4; ++gq) w4[gq] = w2s[h4][gq * 16 + gp];
#pragma unroll
            for (int kk = 0; kk < 4; ++kk) {
                const float4 hv =
                    *(const float4*)&h1s[wave][kq * 4 + kk][h4 * 4];
#pragma unroll
                for (int gq = 0; gq < 4; ++gq) {
                    acc[kk][gq] = fmaf(w4[gq].x, hv.x, acc[kk][gq]);
                    acc[kk][gq] = fmaf(w4[gq].y, hv.y, acc[kk][gq]);
                    acc[kk][gq] = fmaf(w4[gq].z, hv.z, acc[kk][gq]);
                    acc[kk][gq] = fmaf(w4[gq].w, hv.w, acc[kk][gq]);
                }
            }
        }

        // relu, partial mean over this lane's 4 k's, reduce over kq groups
        float s[4];
#pragma unroll
        for (int gq = 0; gq < 4; ++gq)
            s[gq] = fmaxf(acc[0][gq], 0.0f) + fmaxf(acc[1][gq], 0.0f)
                  + fmaxf(acc[2][gq], 0.0f) + fmaxf(acc[3][gq], 0.0f);
#pragma unroll
        for (int off = 16; off <= 32; off <<= 1)
#pragma unroll
            for (int gq = 0; gq < 4; ++gq)
                s[gq] += __shfl_xor(s[gq], off, 64);

        out[p * H_DIM + kq * 16 + gp] = s[kq] * (1.0f / 16.0f);
    }
}

extern "C" void kernel_launch(void* const* d_in, const int* in_sizes, int n_in,
                              void* d_out, int out_size, void* d_ws, size_t ws_size,
                              hipStream_t stream) {
    (void)in_sizes; (void)n_in; (void)out_size; (void)ws_size;
    const float* x  = (const float*)d_in[0];
    const float* W1 = (const float*)d_in[1];
    const float* b1 = (const float*)d_in[2];
    const float* W2 = (const float*)d_in[3];
    const float* b2 = (const float*)d_in[4];
    float* out = (float*)d_out;

    float* xx  = (float*)d_ws;                                  // N floats
    int*   knn = (int*)((char*)d_ws + N_PTS * sizeof(float));   // N*K ints

    const float4* x4 = (const float4*)x;

    xx_kernel <<<N_PTS / 256, 256, 0, stream>>>(x4, xx);
    knn_kernel<<<N_PTS / 16,  256, 0, stream>>>(x4, xx, knn);
    mlp_kernel<<<N_PTS / 16,  256, 0, stream>>>(
        x4, knn, (const float4*)W2, W1, b1, b2, out);
}